// Round 6
// baseline (249.159 us; speedup 1.0000x reference)
//
#include <hip/hip_runtime.h>
#include <math.h>

// Problem constants (match reference)
#define B 32
#define C 4
#define P (360*640)        // 230400 pixels per batch
#define L 5                // MAX_LANES
#define DELTA_V 1.0f
#define DELTA_D 6.0f

// R13 shape: single kernel, per-batch atomic barrier, deadlock-proof grid.
#define S 15               // slots (blocks) per batch -> 480 blocks total
#define V4S (P/(4*S))      // 3840 16B-vectors per slot
#define IT1 (V4S/64)       // 60 per-lane iters, pass 1 (channel-per-wave)
#define IT2 (V4S/256)      // 15 per-thread iters, pass 2
#define SLOTP 16           // padded slot stride in acc[]
#define NPULL (B*S)        // 480 pull partials
#define MAGIC 0x13579BDFu  // flag value (workspace re-poisoned each iter, so
                           // flags != MAGIC at kernel entry; no init needed)

__device__ __forceinline__ float waveReduce(float v) {
#pragma unroll
    for (int off = 32; off; off >>= 1) v += __shfl_down(v, off, 64);
    return v;
}

// ---------------------------------------------------------------------------
// Fused kernel. Pass 1: channel-per-wave segment sums over this block's
// 15360-px slice (labels uchar4 cached to LDS by wave 0). Publish 25 partials
// via device-scope ATOMIC stores + release flag (R5 post-mortem: normal
// stores + grid.sync raced on non-coherent per-XCD L2s). Spin-acquire the
// batch's 15 flags (all 480 blocks co-resident: 480 <= 512 worst-case
// capacity at 2 blocks/CU, so the spin cannot deadlock). Means from atomic
// loads; pass 2 pull loss reads 4 emb planes (L3-warm, just streamed) +
// labels from LDS. Per-batch barrier -> batches pipeline: batch b's pass 2
// overlaps other batches' pass 1.
// ---------------------------------------------------------------------------
__global__ __launch_bounds__(256, 2) void fused_k(const int* __restrict__ tgt,
                                                  const float* __restrict__ emb,
                                                  float* acc,           // atomic RW
                                                  unsigned int* flags,  // atomic RW
                                                  float* __restrict__ meansG,
                                                  float* __restrict__ validG,
                                                  float* __restrict__ cntvG,
                                                  float* __restrict__ pullp) {
    __shared__ uchar4 ltp[V4S];       // packed labels for this slice (15360 B)
    __shared__ float  praw[25];
    __shared__ float4 lmean[L + 1];   // label 0 -> zero mean
    __shared__ float  lvalid[L + 1];  // label 0 -> invalid
    __shared__ float  lred[4];

    const int x = blockIdx.x, b = blockIdx.y;
    const int tid = threadIdx.x;
    const int lane = tid & 63, wave = tid >> 6;

    const int4*   t4 = (const int4*)(tgt + (size_t)b * P) + (size_t)x * V4S;
    const float4* ec = (const float4*)(emb + ((size_t)b * C + wave) * P) + (size_t)x * V4S;

    // ---- pass 1: channel-per-wave segment sums (steady 60-iter stream) ----
    float s[L], n[L];
#pragma unroll
    for (int l = 0; l < L; ++l) { s[l] = 0.f; n[l] = 0.f; }

    auto elem = [&](int tt, float v) {
#pragma unroll
        for (int l = 0; l < L; ++l) {
            float m = (tt == l + 1) ? 1.0f : 0.0f;
            n[l] += m;
            s[l] = fmaf(m, v, s[l]);
        }
    };

#pragma unroll 4
    for (int it = 0; it < IT1; ++it) {
        const int g = it * 64 + lane;
        int4   t = t4[g];
        float4 e = ec[g];
        if (wave == 0)
            ltp[g] = make_uchar4((unsigned char)t.x, (unsigned char)t.y,
                                 (unsigned char)t.z, (unsigned char)t.w);
        elem(t.x, e.x);
        elem(t.y, e.y);
        elem(t.z, e.z);
        elem(t.w, e.w);
    }

    // ---- publish 25 per-slot partials (device-scope atomics) ----
#pragma unroll
    for (int l = 0; l < L; ++l) {
        float r = waveReduce(s[l]);
        if (lane == 0)
            __hip_atomic_store(&acc[((size_t)b * 25 + wave * L + l) * SLOTP + x], r,
                               __ATOMIC_RELAXED, __HIP_MEMORY_SCOPE_AGENT);
    }
    if (wave == 0) {
#pragma unroll
        for (int l = 0; l < L; ++l) {
            float r = waveReduce(n[l]);
            if (lane == 0)
                __hip_atomic_store(&acc[((size_t)b * 25 + 20 + l) * SLOTP + x], r,
                                   __ATOMIC_RELAXED, __HIP_MEMORY_SCOPE_AGENT);
        }
    }
    __syncthreads();                 // all 25 stores + LDS labels done
    if (tid == 0) {
        __threadfence();
        __hip_atomic_store(&flags[b * 16 + x], MAGIC,
                           __ATOMIC_RELEASE, __HIP_MEMORY_SCOPE_AGENT);
    }

    // ---- per-batch barrier: wait for this batch's 15 producers ----
    if (tid < S) {
        while (__hip_atomic_load(&flags[b * 16 + tid],
                                 __ATOMIC_ACQUIRE, __HIP_MEMORY_SCOPE_AGENT) != MAGIC)
            __builtin_amdgcn_s_sleep(8);
    }
    __syncthreads();

    // ---- means: reduce the batch's 25 x 15 partials (atomic loads) ----
    if (tid < 25) {
        float sum = 0.f;
#pragma unroll
        for (int i = 0; i < S; ++i)
            sum += __hip_atomic_load(&acc[((size_t)b * 25 + tid) * SLOTP + i],
                                     __ATOMIC_RELAXED, __HIP_MEMORY_SCOPE_AGENT);
        praw[tid] = sum;
    }
    __syncthreads();
    if (tid < L) {
        const float cnt = praw[20 + tid];
        const bool  vld = cnt > 1.5f;          // integer count > 1
        const float inv = 1.0f / fmaxf(cnt, 1.0f);
        float4 m = make_float4(praw[tid] * inv, praw[5 + tid] * inv,
                               praw[10 + tid] * inv, praw[15 + tid] * inv);
        lmean[tid + 1]  = m;
        lvalid[tid + 1] = vld ? 1.f : 0.f;
        if (x == 0) {                           // publish for finish_k
            *(float4*)(meansG + ((size_t)b * L + tid) * 4) = m;
            validG[b * L + tid] = vld ? 1.f : 0.f;
            cntvG[b * L + tid]  = vld ? cnt : 0.f;
        }
    }
    if (tid == 8) { lmean[0] = make_float4(0.f, 0.f, 0.f, 0.f); lvalid[0] = 0.f; }
    __syncthreads();

    // ---- pass 2: pull loss. Labels from LDS, 4 planes from L3 ----
    const float4* e0 = (const float4*)(emb + ((size_t)b * C + 0) * P) + (size_t)x * V4S;
    const float4* e1 = (const float4*)(emb + ((size_t)b * C + 1) * P) + (size_t)x * V4S;
    const float4* e2 = (const float4*)(emb + ((size_t)b * C + 2) * P) + (size_t)x * V4S;
    const float4* e3 = (const float4*)(emb + ((size_t)b * C + 3) * P) + (size_t)x * V4S;

    float pacc = 0.f;
    auto proc1 = [&](int tt, float v0, float v1, float v2, float v3) {
        float4 m = lmean[tt];
        float d0 = v0 - m.x, d1 = v1 - m.y, d2 = v2 - m.z, d3 = v3 - m.w;
        float sq   = d0*d0 + d1*d1 + d2*d2 + d3*d3;
        float dist = sqrtf(fmaxf(sq, 1e-12f));
        float h    = fmaxf(dist - DELTA_V, 0.f);
        pacc = fmaf(lvalid[tt] * h, h, pacc);
    };

#pragma unroll 3
    for (int it = 0; it < IT2; ++it) {
        const int g = it * 256 + tid;
        uchar4 t  = ltp[g];
        float4 a0 = e0[g], a1 = e1[g], a2 = e2[g], a3 = e3[g];
        proc1(t.x, a0.x, a1.x, a2.x, a3.x);
        proc1(t.y, a0.y, a1.y, a2.y, a3.y);
        proc1(t.z, a0.z, a1.z, a2.z, a3.z);
        proc1(t.w, a0.w, a1.w, a2.w, a3.w);
    }

    float r = waveReduce(pacc);
    if (lane == 0) lred[wave] = r;
    __syncthreads();
    if (tid == 0)
        pullp[b * S + x] = lred[0] + lred[1] + lred[2] + lred[3];
}

// ---------------------------------------------------------------------------
// Kernel 2: final combine — push loss + point_count + pull partial sum
// ---------------------------------------------------------------------------
__global__ __launch_bounds__(256) void finish_k(const float* __restrict__ pullp,
                                                const float* __restrict__ meansG,
                                                const float* __restrict__ validG,
                                                const float* __restrict__ cntvG,
                                                float* __restrict__ out) {
    __shared__ float red[4][4];
    const int tid = threadIdx.x;
    const int lane = tid & 63, wave = tid >> 6;

    float vb = 0.f, has = 0.f;
    if (tid < B) {
        const float* mb = meansG + tid * L * 4;
        const float* vv = validG + tid * L;
        float ssum = 0.f, np = 0.f;
#pragma unroll
        for (int i = 0; i < L; ++i)
#pragma unroll
            for (int j = i + 1; j < L; ++j) {
                float ok = vv[i] * vv[j];
                float d0 = mb[i*4+0] - mb[j*4+0];
                float d1 = mb[i*4+1] - mb[j*4+1];
                float d2 = mb[i*4+2] - mb[j*4+2];
                float d3 = mb[i*4+3] - mb[j*4+3];
                float psq = d0*d0 + d1*d1 + d2*d2 + d3*d3;
                float pd  = sqrtf(fmaxf(psq, 1e-12f));
                float ph  = fmaxf(DELTA_D - pd, 0.f);
                ssum += ok * ph * ph;
                np   += ok;
            }
        if (np > 0.f) { vb = ssum / np; has = 1.f; }
    }
    float pc = (tid < B*L) ? cntvG[tid] : 0.f;
    float ps = 0.f;
    for (int i = tid; i < NPULL; i += 256) ps += pullp[i];

    float rvb = waveReduce(vb);
    float rhs = waveReduce(has);
    float rpc = waveReduce(pc);
    float rps = waveReduce(ps);
    if (lane == 0) { red[wave][0]=rvb; red[wave][1]=rhs; red[wave][2]=rpc; red[wave][3]=rps; }
    __syncthreads();
    if (tid == 0) {
        float svb = red[0][0]+red[1][0]+red[2][0]+red[3][0];
        float shs = red[0][1]+red[1][1]+red[2][1]+red[3][1];
        float spc = red[0][2]+red[1][2]+red[2][2]+red[3][2];
        float sps = red[0][3]+red[1][3]+red[2][3]+red[3][3];
        float var = (shs > 0.f) ? svb / shs : 0.f;              // push loss
        float dl  = (spc > 0.f) ? sps / fmaxf(spc, 1.f) : 0.f;  // pull loss
        out[0] = dl + var;
    }
}

// ---------------------------------------------------------------------------
extern "C" void kernel_launch(void* const* d_in, const int* in_sizes, int n_in,
                              void* d_out, int out_size, void* d_ws, size_t ws_size,
                              hipStream_t stream) {
    const int*   tgt = (const int*)d_in[0];    // targets int32 [B,H,W]
    const float* emb = (const float*)d_in[1];  // embedding fp32 [B,C,H,W]

    // workspace layout (all tiny)
    float*        acc    = (float*)d_ws;                        // B*25*16 = 12800 floats
    unsigned int* flags  = (unsigned int*)(acc + (size_t)B * 25 * SLOTP);  // 512 uints
    float*        meansG = (float*)(flags + (size_t)B * 16);    // 640 floats (16B-aligned)
    float*        validG = meansG + (size_t)B * L * 4;          // 160
    float*        cntvG  = validG + B * L;                      // 160
    float*        pullp  = cntvG + B * L;                       // 480

    fused_k<<<dim3(S, B), 256, 0, stream>>>(tgt, emb, acc, flags,
                                            meansG, validG, cntvG, pullp); // 480 blocks
    finish_k<<<1, 256, 0, stream>>>(pullp, meansG, validG, cntvG, (float*)d_out);
}

// Round 7
// 229.578 us; speedup vs baseline: 1.0853x; 1.0853x over previous
//
#include <hip/hip_runtime.h>
#include <math.h>

// Problem constants (match reference)
#define B 32
#define C 4
#define P (360*640)        // 230400 pixels per batch
#define L 5                // MAX_LANES
#define DELTA_V 1.0f
#define DELTA_D 6.0f

// R14 = best-measured composition:
//   seg  : R4 streaming channel-per-wave (68 us, 24 VGPR, 65% occ)
//   means: R4 tiny per-batch reducer
//   pull : R0 baseline shape (1440 blocks, paired 10-load hoists, 64-VGPR)
//          with a 6-load means prologue instead of the 25x45 reduction
#define CH 75              // seg chunks per batch -> grid (75,32) = 2400 blocks
#define I4 (P/(4*CH))      // 768 16B-vectors per seg chunk
#define IT1 (I4/64)        // 12 seg iterations per lane
#define PSTR CH            // partial chunk-stride (value-major)
#define BLKX 45            // pull chunks per batch -> grid (45,32) = 1440 blocks
#define NPULL (B*BLKX)     // 1440 pull partials

__device__ __forceinline__ float waveReduce(float v) {
#pragma unroll
    for (int off = 32; off; off >>= 1) v += __shfl_down(v, off, 64);
    return v;
}

// ---------------------------------------------------------------------------
// Kernel 1: segment sums (R4-verified, verbatim). Channel-per-wave: wave w
// streams (labels, plane w); label lines L1-hit for waves 1-3. Steady 12-iter
// loop (unroll 2), 24 VGPR, 8 blocks/CU, no __syncthreads. Wave 0 emits
// packed uint8 labels + counts. Partials VALUE-MAJOR:
// partial[(b*25+v)*PSTR+x], v=c*5+l (sums), 20+l (cnt).
// ---------------------------------------------------------------------------
__global__ __launch_bounds__(256, 4) void seg_sums_k(const int* __restrict__ tgt,
                                                     const float* __restrict__ emb,
                                                     float* __restrict__ partial,
                                                     unsigned char* __restrict__ tpk) {
    const int x = blockIdx.x, b = blockIdx.y;
    const int lane = threadIdx.x & 63, wave = threadIdx.x >> 6;

    const int4*   t4 = (const int4*)(tgt + (size_t)b * P) + (size_t)x * I4;
    const float4* ec = (const float4*)(emb + ((size_t)b * C + wave) * P) + (size_t)x * I4;
    uchar4*      tp4 = (uchar4*)(tpk + (size_t)b * P) + (size_t)x * I4;

    float s[L], n[L];
#pragma unroll
    for (int l = 0; l < L; ++l) { s[l] = 0.f; n[l] = 0.f; }

    auto elem = [&](int tt, float v) {
#pragma unroll
        for (int l = 0; l < L; ++l) {
            float m = (tt == l + 1) ? 1.0f : 0.0f;
            n[l] += m;
            s[l] = fmaf(m, v, s[l]);
        }
    };

#pragma unroll 2
    for (int it = 0; it < IT1; ++it) {
        const int g = it * 64 + lane;
        int4   t = t4[g];
        float4 e = ec[g];
        if (wave == 0)
            tp4[g] = make_uchar4((unsigned char)t.x, (unsigned char)t.y,
                                 (unsigned char)t.z, (unsigned char)t.w);
        elem(t.x, e.x);
        elem(t.y, e.y);
        elem(t.z, e.z);
        elem(t.w, e.w);
    }

    // per-wave shuffle reduce, direct global writes (no LDS, no syncthreads)
#pragma unroll
    for (int l = 0; l < L; ++l) {
        float r = waveReduce(s[l]);
        if (lane == 0) partial[((size_t)b * 25 + wave * L + l) * PSTR + x] = r;
    }
    if (wave == 0) {
#pragma unroll
        for (int l = 0; l < L; ++l) {
            float r = waveReduce(n[l]);
            if (lane == 0) partial[((size_t)b * 25 + 20 + l) * PSTR + x] = r;
        }
    }
}

// ---------------------------------------------------------------------------
// Kernel 1.5: reduce partials -> means/valid/counts (R4-verified, verbatim).
// ---------------------------------------------------------------------------
__global__ __launch_bounds__(256) void means_k(const float* __restrict__ partial,
                                               float* __restrict__ meansG,
                                               float* __restrict__ validG,
                                               float* __restrict__ cntvG) {
    __shared__ float praw[25];
    const int b = blockIdx.x;
    const int tid = threadIdx.x;
    const int lane = tid & 63, wave = tid >> 6;

    for (int v = wave; v < 25; v += 4) {
        float sum = 0.f;
        for (int i = lane; i < CH; i += 64)
            sum += partial[((size_t)b * 25 + v) * PSTR + i];
        sum = waveReduce(sum);
        if (lane == 0) praw[v] = sum;
    }
    __syncthreads();
    if (tid < L) {
        const float cnt = praw[20 + tid];
        const bool  vld = cnt > 1.5f;          // integer count > 1
        const float inv = 1.0f / fmaxf(cnt, 1.0f);
        float4 m = make_float4(praw[tid] * inv, praw[5 + tid] * inv,
                               praw[10 + tid] * inv, praw[15 + tid] * inv);
        *(float4*)(meansG + ((size_t)b * L + tid) * 4) = m;
        validG[b * L + tid] = vld ? 1.f : 0.f;
        cntvG[b * L + tid]  = vld ? cnt : 0.f;
    }
}

// ---------------------------------------------------------------------------
// Kernel 2: pull loss — the R0 baseline shape (best pull measured: below the
// 68 us top-5 cutoff at total 216.9). 1440 blocks, paired iterations with 10
// loads hoisted per pair, flat SSA, 64-VGPR envelope. Prologue is now just 6
// loads of the precomputed means (replaces R0's 25x45 partial reduction).
// ---------------------------------------------------------------------------
__global__ __launch_bounds__(256, 4) void pull_k(const unsigned char* __restrict__ tpk,
                                                 const float* __restrict__ emb,
                                                 const float* __restrict__ meansG,
                                                 const float* __restrict__ validG,
                                                 float* __restrict__ pullp) {
    __shared__ float4 lmean[L + 1];   // label 0 -> zero mean
    __shared__ float  lvalid[L + 1];  // label 0 -> invalid
    __shared__ float  lred[4];
    const int xb = blockIdx.x, b = blockIdx.y;
    const int tid = threadIdx.x;
    const int lane = tid & 63, wave = tid >> 6;

    if (tid < L) {
        lmean[tid + 1]  = *(const float4*)(meansG + ((size_t)b * L + tid) * 4);
        lvalid[tid + 1] = validG[b * L + tid];
    }
    if (tid == L) { lmean[0] = make_float4(0.f, 0.f, 0.f, 0.f); lvalid[0] = 0.f; }
    __syncthreads();

    const uchar4* tp4 = (const uchar4*)(tpk + (size_t)b * P);
    const float4* e0  = (const float4*)(emb + ((size_t)b * C + 0) * P);
    const float4* e1  = (const float4*)(emb + ((size_t)b * C + 1) * P);
    const float4* e2  = (const float4*)(emb + ((size_t)b * C + 2) * P);
    const float4* e3  = (const float4*)(emb + ((size_t)b * C + 3) * P);

    float acc = 0.f;
    auto proc1 = [&](int tt, float v0, float v1, float v2, float v3) {
        float4 m = lmean[tt];
        float d0 = v0 - m.x, d1 = v1 - m.y, d2 = v2 - m.z, d3 = v3 - m.w;
        float sq   = d0*d0 + d1*d1 + d2*d2 + d3*d3;
        float dist = sqrtf(fmaxf(sq, 1e-12f));
        float h    = fmaxf(dist - DELTA_V, 0.f);
        acc = fmaf(lvalid[tt] * h, h, acc);
    };
    auto consume = [&](uchar4 t, const float4& a0, const float4& a1,
                       const float4& a2, const float4& a3) {
        proc1(t.x, a0.x, a1.x, a2.x, a3.x);
        proc1(t.y, a0.y, a1.y, a2.y, a3.y);
        proc1(t.z, a0.z, a1.z, a2.z, a3.z);
        proc1(t.w, a0.w, a1.w, a2.w, a3.w);
    };

    {   // pair (0,1)
        const int g0 = xb * 256 + tid, g1 = (xb + BLKX) * 256 + tid;
        uchar4 t0 = tp4[g0], t1 = tp4[g1];
        float4 a0 = e0[g0], a1 = e1[g0], a2 = e2[g0], a3 = e3[g0];
        float4 b0 = e0[g1], b1 = e1[g1], b2 = e2[g1], b3 = e3[g1];
        consume(t0, a0, a1, a2, a3);
        consume(t1, b0, b1, b2, b3);
    }
    {   // pair (2,3)
        const int g0 = (xb + 2*BLKX) * 256 + tid, g1 = (xb + 3*BLKX) * 256 + tid;
        uchar4 t0 = tp4[g0], t1 = tp4[g1];
        float4 a0 = e0[g0], a1 = e1[g0], a2 = e2[g0], a3 = e3[g0];
        float4 b0 = e0[g1], b1 = e1[g1], b2 = e2[g1], b3 = e3[g1];
        consume(t0, a0, a1, a2, a3);
        consume(t1, b0, b1, b2, b3);
    }
    {   // iteration 4
        const int g0 = (xb + 4*BLKX) * 256 + tid;
        uchar4 t0 = tp4[g0];
        float4 a0 = e0[g0], a1 = e1[g0], a2 = e2[g0], a3 = e3[g0];
        consume(t0, a0, a1, a2, a3);
    }

    float r = waveReduce(acc);
    if (lane == 0) lred[wave] = r;
    __syncthreads();
    if (tid == 0)
        pullp[b * BLKX + xb] = lred[0] + lred[1] + lred[2] + lred[3];
}

// ---------------------------------------------------------------------------
// Kernel 3: final combine — push loss + point_count + pull partial sum
// ---------------------------------------------------------------------------
__global__ __launch_bounds__(256) void finish_k(const float* __restrict__ pullp,
                                                const float* __restrict__ meansG,
                                                const float* __restrict__ validG,
                                                const float* __restrict__ cntvG,
                                                float* __restrict__ out) {
    __shared__ float red[4][4];
    const int tid = threadIdx.x;
    const int lane = tid & 63, wave = tid >> 6;

    float vb = 0.f, has = 0.f;
    if (tid < B) {
        const float* mb = meansG + tid * L * 4;
        const float* vv = validG + tid * L;
        float ssum = 0.f, np = 0.f;
#pragma unroll
        for (int i = 0; i < L; ++i)
#pragma unroll
            for (int j = i + 1; j < L; ++j) {
                float ok = vv[i] * vv[j];
                float d0 = mb[i*4+0] - mb[j*4+0];
                float d1 = mb[i*4+1] - mb[j*4+1];
                float d2 = mb[i*4+2] - mb[j*4+2];
                float d3 = mb[i*4+3] - mb[j*4+3];
                float psq = d0*d0 + d1*d1 + d2*d2 + d3*d3;
                float pd  = sqrtf(fmaxf(psq, 1e-12f));
                float ph  = fmaxf(DELTA_D - pd, 0.f);
                ssum += ok * ph * ph;
                np   += ok;
            }
        if (np > 0.f) { vb = ssum / np; has = 1.f; }
    }
    float pc = (tid < B*L) ? cntvG[tid] : 0.f;
    float ps = 0.f;
    for (int i = tid; i < NPULL; i += 256) ps += pullp[i];

    float rvb = waveReduce(vb);
    float rhs = waveReduce(has);
    float rpc = waveReduce(pc);
    float rps = waveReduce(ps);
    if (lane == 0) { red[wave][0]=rvb; red[wave][1]=rhs; red[wave][2]=rpc; red[wave][3]=rps; }
    __syncthreads();
    if (tid == 0) {
        float svb = red[0][0]+red[1][0]+red[2][0]+red[3][0];
        float shs = red[0][1]+red[1][1]+red[2][1]+red[3][1];
        float spc = red[0][2]+red[1][2]+red[2][2]+red[3][2];
        float sps = red[0][3]+red[1][3]+red[2][3]+red[3][3];
        float var = (shs > 0.f) ? svb / shs : 0.f;              // push loss
        float dl  = (spc > 0.f) ? sps / fmaxf(spc, 1.f) : 0.f;  // pull loss
        out[0] = dl + var;
    }
}

// ---------------------------------------------------------------------------
extern "C" void kernel_launch(void* const* d_in, const int* in_sizes, int n_in,
                              void* d_out, int out_size, void* d_ws, size_t ws_size,
                              hipStream_t stream) {
    const int*   tgt = (const int*)d_in[0];    // targets int32 [B,H,W]
    const float* emb = (const float*)d_in[1];  // embedding fp32 [B,C,H,W]

    // workspace layout: packed labels first (B*P bytes, 16B-aligned size),
    // then float scratch
    unsigned char* tpk = (unsigned char*)d_ws;                 // 7372800 B
    float* fbase   = (float*)((char*)d_ws + (size_t)B * P);    // 7372800 % 16 == 0
    float* partial = fbase;                                    // B*25*75 = 60000 floats
    float* meansG  = partial + (size_t)B * 25 * PSTR;          // 640 (16B-aligned)
    float* validG  = meansG + (size_t)B * L * 4;               // 160
    float* cntvG   = validG + B * L;                           // 160
    float* pullp   = cntvG + B * L;                            // 1440
    // total ws use: ~7.6 MB

    seg_sums_k<<<dim3(CH, B), 256, 0, stream>>>(tgt, emb, partial, tpk);   // 2400 blocks
    means_k<<<dim3(B), 256, 0, stream>>>(partial, meansG, validG, cntvG);  // 32 blocks
    pull_k<<<dim3(BLKX, B), 256, 0, stream>>>(tpk, emb, meansG, validG, pullp); // 1440 blocks
    finish_k<<<1, 256, 0, stream>>>(pullp, meansG, validG, cntvG, (float*)d_out);
}

// Round 8
// 225.107 us; speedup vs baseline: 1.1068x; 1.0199x over previous
//
#include <hip/hip_runtime.h>
#include <math.h>

// Problem constants (match reference)
#define B 32
#define C 4
#define P (360*640)        // 230400 pixels per batch
#define L 5                // MAX_LANES
#define DELTA_V 1.0f
#define DELTA_D 6.0f

// R15 = 3-launch graph (launch count ~10 us each; 4-launch rounds were all
// ~10-13 us worse) with the best-measured components:
//   seg  : R4 streaming channel-per-wave (68-70 us proven, 24 VGPR, 60% occ)
//   pull : R0 baseline shape (best pull measured) with the partial-reduction
//          prologue done per-block (no separate means_k launch)
#define CH 75              // seg chunks per batch -> grid (75,32) = 2400 blocks
#define I4 (P/(4*CH))      // 768 16B-vectors per seg chunk
#define IT1 (I4/64)        // 12 seg iterations per lane
#define PSTR CH            // partial chunk-stride (value-major)
#define BLKX 45            // pull chunks per batch -> grid (45,32) = 1440 blocks
#define NPULL (B*BLKX)     // 1440 pull partials

__device__ __forceinline__ float waveReduce(float v) {
#pragma unroll
    for (int off = 32; off; off >>= 1) v += __shfl_down(v, off, 64);
    return v;
}

// ---------------------------------------------------------------------------
// Kernel 1: segment sums (R4-verified, verbatim). Channel-per-wave: wave w
// streams (labels, plane w); label lines L1-hit for waves 1-3. Steady 12-iter
// loop (unroll 2), 24 VGPR, no __syncthreads. Runs in the poison-fill's HBM
// write-drain shadow (~69 us floor regardless of structure — R2/R4/R7).
// Wave 0 emits packed uint8 labels + counts. Partials VALUE-MAJOR:
// partial[(b*25+v)*PSTR+x], v=c*5+l (sums), 20+l (cnt).
// ---------------------------------------------------------------------------
__global__ __launch_bounds__(256, 4) void seg_sums_k(const int* __restrict__ tgt,
                                                     const float* __restrict__ emb,
                                                     float* __restrict__ partial,
                                                     unsigned char* __restrict__ tpk) {
    const int x = blockIdx.x, b = blockIdx.y;
    const int lane = threadIdx.x & 63, wave = threadIdx.x >> 6;

    const int4*   t4 = (const int4*)(tgt + (size_t)b * P) + (size_t)x * I4;
    const float4* ec = (const float4*)(emb + ((size_t)b * C + wave) * P) + (size_t)x * I4;
    uchar4*      tp4 = (uchar4*)(tpk + (size_t)b * P) + (size_t)x * I4;

    float s[L], n[L];
#pragma unroll
    for (int l = 0; l < L; ++l) { s[l] = 0.f; n[l] = 0.f; }

    auto elem = [&](int tt, float v) {
#pragma unroll
        for (int l = 0; l < L; ++l) {
            float m = (tt == l + 1) ? 1.0f : 0.0f;
            n[l] += m;
            s[l] = fmaf(m, v, s[l]);
        }
    };

#pragma unroll 2
    for (int it = 0; it < IT1; ++it) {
        const int g = it * 64 + lane;
        int4   t = t4[g];
        float4 e = ec[g];
        if (wave == 0)
            tp4[g] = make_uchar4((unsigned char)t.x, (unsigned char)t.y,
                                 (unsigned char)t.z, (unsigned char)t.w);
        elem(t.x, e.x);
        elem(t.y, e.y);
        elem(t.z, e.z);
        elem(t.w, e.w);
    }

    // per-wave shuffle reduce, direct global writes (no LDS, no syncthreads)
#pragma unroll
    for (int l = 0; l < L; ++l) {
        float r = waveReduce(s[l]);
        if (lane == 0) partial[((size_t)b * 25 + wave * L + l) * PSTR + x] = r;
    }
    if (wave == 0) {
#pragma unroll
        for (int l = 0; l < L; ++l) {
            float r = waveReduce(n[l]);
            if (lane == 0) partial[((size_t)b * 25 + 20 + l) * PSTR + x] = r;
        }
    }
}

// ---------------------------------------------------------------------------
// Kernel 2: pull loss — R0 baseline shape (3-launch graph: prologue reduces
// the batch's value-major partials in-block, xb==0 publishes means for
// finish_k; no separate means kernel). Main loop: packed labels + 4 planes,
// paired iterations, 10 loads hoisted per pair, flat SSA, 64-VGPR envelope.
// Prologue adapted to CH=75 partials: strided 75-entry wave reduce (~7.5 KB
// L2-hot reads per block).
// ---------------------------------------------------------------------------
__global__ __launch_bounds__(256, 4) void pull_k(const unsigned char* __restrict__ tpk,
                                                 const float* __restrict__ emb,
                                                 const float* __restrict__ partial,
                                                 float* __restrict__ meansG,
                                                 float* __restrict__ validG,
                                                 float* __restrict__ cntvG,
                                                 float* __restrict__ pullp) {
    __shared__ float  praw[25];
    __shared__ float4 lmean[L + 1];   // label 0 -> zero mean
    __shared__ float  lvalid[L + 1];  // label 0 -> invalid
    __shared__ float  lred[4];
    const int xb = blockIdx.x, b = blockIdx.y;
    const int tid = threadIdx.x;
    const int lane = tid & 63, wave = tid >> 6;

    // ---- prologue: reduce partials (value-major, 75 chunks) for batch b ----
    for (int v = wave; v < 25; v += 4) {
        float pv = 0.f;
        for (int i = lane; i < CH; i += 64)
            pv += partial[((size_t)b * 25 + v) * PSTR + i];
        pv = waveReduce(pv);
        if (lane == 0) praw[v] = pv;
    }
    __syncthreads();
    if (tid < L) {
        const float cnt = praw[20 + tid];
        const bool  vld = cnt > 1.5f;          // integer count > 1
        const float inv = 1.0f / fmaxf(cnt, 1.0f);
        float4 m = make_float4(praw[tid] * inv, praw[5 + tid] * inv,
                               praw[10 + tid] * inv, praw[15 + tid] * inv);
        lmean[tid + 1]  = m;
        lvalid[tid + 1] = vld ? 1.f : 0.f;
        if (xb == 0) {                          // publish for finish_k
            *(float4*)(meansG + ((size_t)b * L + tid) * 4) = m;
            validG[b * L + tid] = vld ? 1.f : 0.f;
            cntvG[b * L + tid]  = vld ? cnt : 0.f;
        }
    }
    if (tid == 8) { lmean[0] = make_float4(0.f, 0.f, 0.f, 0.f); lvalid[0] = 0.f; }
    __syncthreads();

    // ---- main: packed labels + 4 planes, paired iterations (no rotation) ----
    const uchar4* tp4 = (const uchar4*)(tpk + (size_t)b * P);
    const float4* e0  = (const float4*)(emb + ((size_t)b * C + 0) * P);
    const float4* e1  = (const float4*)(emb + ((size_t)b * C + 1) * P);
    const float4* e2  = (const float4*)(emb + ((size_t)b * C + 2) * P);
    const float4* e3  = (const float4*)(emb + ((size_t)b * C + 3) * P);

    float acc = 0.f;
    auto proc1 = [&](int tt, float v0, float v1, float v2, float v3) {
        float4 m = lmean[tt];
        float d0 = v0 - m.x, d1 = v1 - m.y, d2 = v2 - m.z, d3 = v3 - m.w;
        float sq   = d0*d0 + d1*d1 + d2*d2 + d3*d3;
        float dist = sqrtf(fmaxf(sq, 1e-12f));
        float h    = fmaxf(dist - DELTA_V, 0.f);
        acc = fmaf(lvalid[tt] * h, h, acc);
    };
    auto consume = [&](uchar4 t, const float4& a0, const float4& a1,
                       const float4& a2, const float4& a3) {
        proc1(t.x, a0.x, a1.x, a2.x, a3.x);
        proc1(t.y, a0.y, a1.y, a2.y, a3.y);
        proc1(t.z, a0.z, a1.z, a2.z, a3.z);
        proc1(t.w, a0.w, a1.w, a2.w, a3.w);
    };

    {   // pair (0,1)
        const int g0 = xb * 256 + tid, g1 = (xb + BLKX) * 256 + tid;
        uchar4 t0 = tp4[g0], t1 = tp4[g1];
        float4 a0 = e0[g0], a1 = e1[g0], a2 = e2[g0], a3 = e3[g0];
        float4 b0 = e0[g1], b1 = e1[g1], b2 = e2[g1], b3 = e3[g1];
        consume(t0, a0, a1, a2, a3);
        consume(t1, b0, b1, b2, b3);
    }
    {   // pair (2,3)
        const int g0 = (xb + 2*BLKX) * 256 + tid, g1 = (xb + 3*BLKX) * 256 + tid;
        uchar4 t0 = tp4[g0], t1 = tp4[g1];
        float4 a0 = e0[g0], a1 = e1[g0], a2 = e2[g0], a3 = e3[g0];
        float4 b0 = e0[g1], b1 = e1[g1], b2 = e2[g1], b3 = e3[g1];
        consume(t0, a0, a1, a2, a3);
        consume(t1, b0, b1, b2, b3);
    }
    {   // iteration 4
        const int g0 = (xb + 4*BLKX) * 256 + tid;
        uchar4 t0 = tp4[g0];
        float4 a0 = e0[g0], a1 = e1[g0], a2 = e2[g0], a3 = e3[g0];
        consume(t0, a0, a1, a2, a3);
    }

    float r = waveReduce(acc);
    if (lane == 0) lred[wave] = r;
    __syncthreads();
    if (tid == 0)
        pullp[b * BLKX + xb] = lred[0] + lred[1] + lred[2] + lred[3];
}

// ---------------------------------------------------------------------------
// Kernel 3: final combine — push loss + point_count + pull partial sum
// ---------------------------------------------------------------------------
__global__ __launch_bounds__(256) void finish_k(const float* __restrict__ pullp,
                                                const float* __restrict__ meansG,
                                                const float* __restrict__ validG,
                                                const float* __restrict__ cntvG,
                                                float* __restrict__ out) {
    __shared__ float red[4][4];
    const int tid = threadIdx.x;
    const int lane = tid & 63, wave = tid >> 6;

    float vb = 0.f, has = 0.f;
    if (tid < B) {
        const float* mb = meansG + tid * L * 4;
        const float* vv = validG + tid * L;
        float ssum = 0.f, np = 0.f;
#pragma unroll
        for (int i = 0; i < L; ++i)
#pragma unroll
            for (int j = i + 1; j < L; ++j) {
                float ok = vv[i] * vv[j];
                float d0 = mb[i*4+0] - mb[j*4+0];
                float d1 = mb[i*4+1] - mb[j*4+1];
                float d2 = mb[i*4+2] - mb[j*4+2];
                float d3 = mb[i*4+3] - mb[j*4+3];
                float psq = d0*d0 + d1*d1 + d2*d2 + d3*d3;
                float pd  = sqrtf(fmaxf(psq, 1e-12f));
                float ph  = fmaxf(DELTA_D - pd, 0.f);
                ssum += ok * ph * ph;
                np   += ok;
            }
        if (np > 0.f) { vb = ssum / np; has = 1.f; }
    }
    float pc = (tid < B*L) ? cntvG[tid] : 0.f;
    float ps = 0.f;
    for (int i = tid; i < NPULL; i += 256) ps += pullp[i];

    float rvb = waveReduce(vb);
    float rhs = waveReduce(has);
    float rpc = waveReduce(pc);
    float rps = waveReduce(ps);
    if (lane == 0) { red[wave][0]=rvb; red[wave][1]=rhs; red[wave][2]=rpc; red[wave][3]=rps; }
    __syncthreads();
    if (tid == 0) {
        float svb = red[0][0]+red[1][0]+red[2][0]+red[3][0];
        float shs = red[0][1]+red[1][1]+red[2][1]+red[3][1];
        float spc = red[0][2]+red[1][2]+red[2][2]+red[3][2];
        float sps = red[0][3]+red[1][3]+red[2][3]+red[3][3];
        float var = (shs > 0.f) ? svb / shs : 0.f;              // push loss
        float dl  = (spc > 0.f) ? sps / fmaxf(spc, 1.f) : 0.f;  // pull loss
        out[0] = dl + var;
    }
}

// ---------------------------------------------------------------------------
extern "C" void kernel_launch(void* const* d_in, const int* in_sizes, int n_in,
                              void* d_out, int out_size, void* d_ws, size_t ws_size,
                              hipStream_t stream) {
    const int*   tgt = (const int*)d_in[0];    // targets int32 [B,H,W]
    const float* emb = (const float*)d_in[1];  // embedding fp32 [B,C,H,W]

    // workspace layout: packed labels first (B*P bytes, 16B-aligned size),
    // then float scratch
    unsigned char* tpk = (unsigned char*)d_ws;                 // 7372800 B
    float* fbase   = (float*)((char*)d_ws + (size_t)B * P);    // 7372800 % 16 == 0
    float* partial = fbase;                                    // B*25*75 = 60000 floats
    float* meansG  = partial + (size_t)B * 25 * PSTR;          // 640 (16B-aligned)
    float* validG  = meansG + (size_t)B * L * 4;               // 160
    float* cntvG   = validG + B * L;                           // 160
    float* pullp   = cntvG + B * L;                            // 1440
    // total ws use: ~7.6 MB

    seg_sums_k<<<dim3(CH, B), 256, 0, stream>>>(tgt, emb, partial, tpk);   // 2400 blocks
    pull_k<<<dim3(BLKX, B), 256, 0, stream>>>(tpk, emb, partial,
                                              meansG, validG, cntvG, pullp); // 1440 blocks
    finish_k<<<1, 256, 0, stream>>>(pullp, meansG, validG, cntvG, (float*)d_out);
}